// Round 1
// baseline (230.865 us; speedup 1.0000x reference)
//
#include <hip/hip_runtime.h>
#include <math.h>

#define N 1024
#define TB 16

__device__ __forceinline__ float prelu(float v, float a) { return v >= 0.f ? v : a * v; }

__global__ __launch_bounds__(256) void precond_fused(
    const float* __restrict__ xg, const int* __restrict__ maskg,
    const float* __restrict__ w1, const float* __restrict__ b1, const float* __restrict__ a1p,
    const float* __restrict__ w2, const float* __restrict__ b2, const float* __restrict__ a2p,
    const float* __restrict__ w3, const float* __restrict__ b3, const float* __restrict__ a3p,
    const float* __restrict__ w4, const float* __restrict__ b4p,
    float* __restrict__ out)
{
    // LDS staging
    __shared__ __align__(16) float sW2[512];        // [(kh*2+kw)][i][oc=16]
    __shared__ __align__(16) float sW3[512];        // [(kh*2+kw)][i][oc=8]
    __shared__ __align__(16) float h1s[324][12];    // 18x18 positions, 8ch used (pad->12 for banks/alignment)
    __shared__ __align__(16) float h2s[289][20];    // 17x17 positions, 16ch used (pad->20)
    __shared__ float ms[324];                       // mask (0/1) at h1 positions
    __shared__ float m2s[289];                      // spread mask at h2 positions

    const int tid = threadIdx.x;
    const int bz  = blockIdx.z;
    const int ty0 = blockIdx.y * TB;
    const int tx0 = blockIdx.x * TB;

    // --- stage transposed weights into LDS ---
    for (int t = tid; t < 512; t += 256) {
        // w2 flat [o][i][kh][kw], o in 0..15
        int o2 = t >> 5, i2 = (t >> 2) & 7;
        int kh = (t >> 1) & 1, kw = t & 1;
        sW2[((kh * 2 + kw) * 8 + i2) * 16 + o2] = w2[t];
        // w3 flat [o][i][kh][kw], o in 0..7
        int o3 = t >> 6, i3 = (t >> 2) & 15;
        sW3[((kh * 2 + kw) * 16 + i3) * 8 + o3] = w3[t];
    }

    const float a1 = a1p[0], a2 = a2p[0], a3 = a3p[0];

    // --- Phase A: h1 (masked, PReLU'd) + mask into LDS ---
    // region rows [ty0-1, ty0+16], cols [tx0-1, tx0+16]  (18x18)
    for (int p = tid; p < 324; p += 256) {
        int dy = p / 18, dx = p % 18;
        int gy = ty0 - 1 + dy, gx = tx0 - 1 + dx;
        float mv = 0.f, xv = 0.f;
        if (gy >= 0 && gy < N && gx >= 0 && gx < N) {
            size_t idx = ((size_t)bz * N + gy) * N + gx;
            mv = (maskg[idx] > 0) ? 1.f : 0.f;
            xv = xg[idx];
        }
        ms[p] = mv;
#pragma unroll
        for (int c = 0; c < 8; ++c) {
            float v = fmaf(xv, w1[c], b1[c]);
            v = prelu(v, a1);
            h1s[p][c] = mv * v;   // h1 = m ? prelu(x*w1+b1) : 0   (m^2 = m)
        }
#pragma unroll
        for (int c = 8; c < 12; ++c) h1s[p][c] = 0.f;
    }
    __syncthreads();

    // --- Phase B: h2 at 17x17 positions (global y2 = ty0+dy2, x2 = tx0-1+dx2) ---
    for (int p = tid; p < 289; p += 256) {
        int dy2 = p / 17, dx2 = p % 17;
        int gx2 = tx0 - 1 + dx2;                 // valid x2 range: [0, N-2]
        bool valid = (gx2 >= 0) && (gx2 <= N - 2);   // y2 always in [0,N]

        float acc[16];
#pragma unroll
        for (int o = 0; o < 16; ++o) acc[o] = b2[o];
        float m2v = 0.f;

#pragma unroll
        for (int kh = 0; kh < 2; ++kh) {
#pragma unroll
            for (int kw = 0; kw < 2; ++kw) {
                int h1i = (dy2 + kh) * 18 + (dx2 + kw);
                m2v = fmaxf(m2v, ms[h1i]);
                const float4 ha = *(const float4*)&h1s[h1i][0];
                const float4 hb = *(const float4*)&h1s[h1i][4];
                const float hv[8] = {ha.x, ha.y, ha.z, ha.w, hb.x, hb.y, hb.z, hb.w};
                const float* wbase = &sW2[(kh * 2 + kw) * 128];
#pragma unroll
                for (int i = 0; i < 8; ++i) {
                    float h = hv[i];
                    const float4* wv = (const float4*)&wbase[i * 16];
#pragma unroll
                    for (int q = 0; q < 4; ++q) {
                        float4 w = wv[q];
                        acc[q * 4 + 0] = fmaf(h, w.x, acc[q * 4 + 0]);
                        acc[q * 4 + 1] = fmaf(h, w.y, acc[q * 4 + 1]);
                        acc[q * 4 + 2] = fmaf(h, w.z, acc[q * 4 + 2]);
                        acc[q * 4 + 3] = fmaf(h, w.w, acc[q * 4 + 3]);
                    }
                }
            }
        }
        if (!valid) m2v = 0.f;
        m2s[p] = m2v;
#pragma unroll
        for (int o = 0; o < 16; ++o)
            h2s[p][o] = m2v * prelu(acc[o], a2);   // h2 = m2 ? prelu(raw) : 0
    }
    __syncthreads();

    // --- Phase C: h3 + h4 + epilogue, one output pixel per thread ---
    {
        int ty = tid >> 4, tx = tid & 15;
        float acc[8];
#pragma unroll
        for (int o = 0; o < 8; ++o) acc[o] = b3[o];
        float m3v = 0.f;

#pragma unroll
        for (int kh = 0; kh < 2; ++kh) {
#pragma unroll
            for (int kw = 0; kw < 2; ++kw) {
                int h2i = (ty + kh) * 17 + (tx + kw);
                m3v = fmaxf(m3v, m2s[h2i]);
                const float* wbase = &sW3[(kh * 2 + kw) * 128];
#pragma unroll
                for (int iq = 0; iq < 4; ++iq) {
                    float4 hq = *(const float4*)&h2s[h2i][iq * 4];
                    float hvv[4] = {hq.x, hq.y, hq.z, hq.w};
#pragma unroll
                    for (int u = 0; u < 4; ++u) {
                        int i = iq * 4 + u;
                        float h = hvv[u];
                        const float4 wA = *(const float4*)&wbase[i * 8];
                        const float4 wB = *(const float4*)&wbase[i * 8 + 4];
                        acc[0] = fmaf(h, wA.x, acc[0]);
                        acc[1] = fmaf(h, wA.y, acc[1]);
                        acc[2] = fmaf(h, wA.z, acc[2]);
                        acc[3] = fmaf(h, wA.w, acc[3]);
                        acc[4] = fmaf(h, wB.x, acc[4]);
                        acc[5] = fmaf(h, wB.y, acc[5]);
                        acc[6] = fmaf(h, wB.z, acc[6]);
                        acc[7] = fmaf(h, wB.w, acc[7]);
                    }
                }
            }
        }

        float outv = b4p[0];
#pragma unroll
        for (int o = 0; o < 8; ++o) {
            float h3 = prelu(acc[o], a3);
            outv = fmaf(h3, w4[o], outv);
        }
        outv *= m3v;   // layer-4 mask (h3 masking folds in since m3^2 = m3)

        int y = ty0 + ty, x = tx0 + tx;
        if (y < x) {
            outv = 0.f;
        } else if (y == x && m3v > 0.f) {
            // stable softplus = max(v,0) + log1p(exp(-|v|))
            outv = fmaxf(outv, 0.f) + log1pf(expf(-fabsf(outv)));
        }
        out[((size_t)bz * N + y) * N + x] = outv;
    }
}

extern "C" void kernel_launch(void* const* d_in, const int* in_sizes, int n_in,
                              void* d_out, int out_size, void* d_ws, size_t ws_size,
                              hipStream_t stream) {
    const float* x    = (const float*)d_in[0];
    const int*   mask = (const int*)  d_in[1];
    const float* w1   = (const float*)d_in[2];
    const float* b1   = (const float*)d_in[3];
    const float* a1   = (const float*)d_in[4];
    const float* w2   = (const float*)d_in[5];
    const float* b2   = (const float*)d_in[6];
    const float* a2   = (const float*)d_in[7];
    const float* w3   = (const float*)d_in[8];
    const float* b3   = (const float*)d_in[9];
    const float* a3   = (const float*)d_in[10];
    const float* w4   = (const float*)d_in[11];
    const float* b4   = (const float*)d_in[12];
    float* out = (float*)d_out;

    dim3 grid(N / TB, N / TB, 2);
    precond_fused<<<grid, 256, 0, stream>>>(x, mask, w1, b1, a1, w2, b2, a2,
                                            w3, b3, a3, w4, b4, out);
}

// Round 2
// 45.003 us; speedup vs baseline: 5.1299x; 5.1299x over previous
//
#include <hip/hip_runtime.h>
#include <math.h>

#define N 1024
#define TB 16

typedef __attribute__((ext_vector_type(8))) short short8;
typedef __attribute__((ext_vector_type(4))) short short4v;
typedef __attribute__((ext_vector_type(4))) float f32x4;

__device__ __forceinline__ float prelu(float v, float a) { return v >= 0.f ? v : a * v; }

// f32 -> bf16 round-to-nearest-even
__device__ __forceinline__ short f2bf(float f) {
    union { float f; unsigned u; } c; c.f = f;
    unsigned r = c.u + 0x7FFFu + ((c.u >> 16) & 1u);
    return (short)(r >> 16);
}

__global__ __launch_bounds__(256) void precond_mfma(
    const float* __restrict__ xg, const int* __restrict__ maskg,
    const float* __restrict__ w1, const float* __restrict__ b1, const float* __restrict__ a1p,
    const float* __restrict__ w2, const float* __restrict__ b2, const float* __restrict__ a2p,
    const float* __restrict__ w3, const float* __restrict__ b3, const float* __restrict__ a3p,
    const float* __restrict__ w4, const float* __restrict__ b4p,
    float* __restrict__ out)
{
    // weights as bf16, A-fragment-friendly layout
    __shared__ __align__(16) short sW2[512];    // [oc=16][k=32], k = khkw*8 + ic
    __shared__ __align__(16) short sW3[1024];   // [oc=16][k=64], k = khkw*16 + ic (oc>=8 zero)
    __shared__ __align__(16) short h1s[324 * 8];   // [pos 18x18][8ch] bf16, 16B/pos
    __shared__ __align__(16) short h2s[289 * 24];  // [pos 17x17][16ch used, pad->24] bf16, 48B/pos
    __shared__ float ms[324];    // mask at h1 positions
    __shared__ float m2s[289];   // spread mask at h2 positions

    const int tid = threadIdx.x;
    const int bz  = blockIdx.z;
    const int ty0 = blockIdx.y * TB, tx0 = blockIdx.x * TB;
    const float a1 = a1p[0], a2 = a2p[0], a3 = a3p[0];

    // --- stage transposed bf16 weights ---
    for (int t = tid; t < 512; t += 256) {
        int o = t >> 5, khkw = (t >> 3) & 3, i = t & 7;
        sW2[t] = f2bf(w2[((o * 8 + i) * 2 + (khkw >> 1)) * 2 + (khkw & 1)]);
    }
    for (int t = tid; t < 1024; t += 256) {
        int oc = t >> 6, k = t & 63, khkw = k >> 4, i = k & 15;
        sW3[t] = (oc < 8) ? f2bf(w3[((oc * 16 + i) * 2 + (khkw >> 1)) * 2 + (khkw & 1)]) : (short)0;
    }

    // --- Phase A: h1 (masked, PReLU'd, bf16) + mask into LDS (18x18 halo) ---
    for (int p = tid; p < 324; p += 256) {
        int dy = p / 18, dx = p - dy * 18;
        int gy = ty0 - 1 + dy, gx = tx0 - 1 + dx;
        float mv = 0.f, xv = 0.f;
        if (gy >= 0 && gy < N && gx >= 0 && gx < N) {
            size_t idx = ((size_t)bz * N + gy) * N + gx;
            mv = (maskg[idx] > 0) ? 1.f : 0.f;
            xv = xg[idx];
        }
        ms[p] = mv;
        short8 hv;
#pragma unroll
        for (int c = 0; c < 8; ++c) hv[c] = f2bf(mv * prelu(fmaf(xv, w1[c], b1[c]), a1));
        *(short8*)&h1s[p * 8] = hv;
    }
    __syncthreads();

    const int lane = tid & 63, wid = tid >> 6;
    const int c16 = lane & 15, g = lane >> 4;

    // --- Phase B: h2 at 17x17 positions via MFMA (K=32: 4 khkw x 8 ic) ---
    {
        // A fragment: lane holds W2[oc=c16][k = g*8 .. g*8+7]
        short8 a2f = *(const short8*)&sW2[c16 * 32 + g * 8];
        const int kh = g >> 1, kw = g & 1;  // this lane's khkw group = g
        f32x4 bias2;
#pragma unroll
        for (int r = 0; r < 4; ++r) bias2[r] = b2[g * 4 + r];

        for (int G = wid * 5; G < wid * 5 + 5; ++G) {   // 20 groups of 16 positions
            int p = G * 16 + c16;
            bool valid = p < 289;
            int pc = valid ? p : 288;
            int dy2 = pc / 17, dx2 = pc - dy2 * 17;
            // B fragment: h1 window value block for column pos=pc, k-rows g*8..g*8+7
            short8 bf = *(const short8*)&h1s[((dy2 + kh) * 18 + dx2 + kw) * 8];
            f32x4 acc = __builtin_amdgcn_mfma_f32_16x16x32_bf16(a2f, bf, bias2, 0, 0, 0);
            // epilogue: spread mask, PReLU, pack, store (lane owns col pc, oc = g*4+r)
            float m2v = fmaxf(fmaxf(ms[dy2 * 18 + dx2],       ms[dy2 * 18 + dx2 + 1]),
                              fmaxf(ms[(dy2 + 1) * 18 + dx2], ms[(dy2 + 1) * 18 + dx2 + 1]));
            int gx2 = tx0 - 1 + dx2;
            if (gx2 < 0 || gx2 > N - 2) m2v = 0.f;
            if (valid) {
                short4v hv;
#pragma unroll
                for (int r = 0; r < 4; ++r) hv[r] = f2bf(m2v * prelu(acc[r], a2));
                *(short4v*)&h2s[pc * 24 + g * 4] = hv;
                if (g == 0) m2s[pc] = m2v;
            }
        }
    }
    __syncthreads();

    // --- Phase C: h3 via 2 chained MFMAs (K=64) + layer4 + epilogue ---
    {
        short8 a3f0 = *(const short8*)&sW3[c16 * 64 + g * 8];        // k 0..31  (kh=0)
        short8 a3f1 = *(const short8*)&sW3[c16 * 64 + 32 + g * 8];   // k 32..63 (kh=1)
        const int kw = g >> 1, ic8 = g & 1;
        f32x4 bias3;
        float w4r[4];
#pragma unroll
        for (int r = 0; r < 4; ++r) {
            bias3[r] = (g < 2) ? b3[g * 4 + r] : 0.f;
            w4r[r]   = (g < 2) ? w4[g * 4 + r] : 0.f;
        }
        const float b4 = b4p[0];

        for (int G = wid * 4; G < wid * 4 + 4; ++G) {   // 16 output rows
            // B fragments: h2[(G+kh)*17 + tx + kw][ic8*8 .. +7]
            short8 bf0 = *(const short8*)&h2s[((G + 0) * 17 + c16 + kw) * 24 + ic8 * 8];
            short8 bf1 = *(const short8*)&h2s[((G + 1) * 17 + c16 + kw) * 24 + ic8 * 8];
            f32x4 acc = __builtin_amdgcn_mfma_f32_16x16x32_bf16(a3f0, bf0, bias3, 0, 0, 0);
            acc = __builtin_amdgcn_mfma_f32_16x16x32_bf16(a3f1, bf1, acc, 0, 0, 0);

            // layer 4: partial dot over this lane's 4 oc, then cross-lane sum over g
            float partial = 0.f;
#pragma unroll
            for (int r = 0; r < 4; ++r) partial = fmaf(prelu(acc[r], a3), w4r[r], partial);
            partial += __shfl_xor(partial, 16, 64);
            partial += __shfl_xor(partial, 32, 64);

            float m3v = fmaxf(fmaxf(m2s[G * 17 + c16],       m2s[G * 17 + c16 + 1]),
                              fmaxf(m2s[(G + 1) * 17 + c16], m2s[(G + 1) * 17 + c16 + 1]));
            float outv = (partial + b4) * m3v;

            int y = ty0 + G, x = tx0 + c16;
            if (y < x) {
                outv = 0.f;
            } else if (y == x && m3v > 0.f) {
                outv = fmaxf(outv, 0.f) + log1pf(expf(-fabsf(outv)));
            }
            if (g == 0) out[((size_t)bz * N + y) * N + x] = outv;
        }
    }
}

extern "C" void kernel_launch(void* const* d_in, const int* in_sizes, int n_in,
                              void* d_out, int out_size, void* d_ws, size_t ws_size,
                              hipStream_t stream) {
    const float* x    = (const float*)d_in[0];
    const int*   mask = (const int*)  d_in[1];
    const float* w1   = (const float*)d_in[2];
    const float* b1   = (const float*)d_in[3];
    const float* a1   = (const float*)d_in[4];
    const float* w2   = (const float*)d_in[5];
    const float* b2   = (const float*)d_in[6];
    const float* a2   = (const float*)d_in[7];
    const float* w3   = (const float*)d_in[8];
    const float* b3   = (const float*)d_in[9];
    const float* a3   = (const float*)d_in[10];
    const float* w4   = (const float*)d_in[11];
    const float* b4   = (const float*)d_in[12];
    float* out = (float*)d_out;

    dim3 grid(N / TB, N / TB, 2);
    precond_mfma<<<grid, 256, 0, stream>>>(x, mask, w1, b1, a1, w2, b2, a2,
                                           w3, b3, a3, w4, b4, out);
}

// Round 3
// 34.215 us; speedup vs baseline: 6.7475x; 1.3153x over previous
//
#include <hip/hip_runtime.h>
#include <hip/hip_bf16.h>
#include <math.h>

#define N 1024
#define TB 16

typedef __attribute__((ext_vector_type(8))) short short8;
typedef __attribute__((ext_vector_type(4))) short short4v;
typedef __attribute__((ext_vector_type(4))) float f32x4;

// PReLU via max/min: max(v,0) + a*min(v,0)  (v_max, v_min, v_fma)
__device__ __forceinline__ float prelu(float v, float a) {
    return fmaxf(v, 0.f) + a * fminf(v, 0.f);
}

// f32 -> bf16 RNE via hardware cvt
__device__ __forceinline__ short f2bf(float f) {
    return (short)__bfloat16_as_ushort(__float2bfloat16(f));
}

__global__ __launch_bounds__(256) void precond_mfma(
    const float* __restrict__ xg, const int* __restrict__ maskg,
    const float* __restrict__ w1, const float* __restrict__ b1, const float* __restrict__ a1p,
    const float* __restrict__ w2, const float* __restrict__ b2, const float* __restrict__ a2p,
    const float* __restrict__ w3, const float* __restrict__ b3, const float* __restrict__ a3p,
    const float* __restrict__ w4, const float* __restrict__ b4p,
    float* __restrict__ out)
{
    const int tid = threadIdx.x;
    const int bz  = blockIdx.z;
    const int ty0 = blockIdx.y * TB, tx0 = blockIdx.x * TB;

    // ---- Early exit: tile entirely above the diagonal -> output is all zeros ----
    if (blockIdx.y < blockIdx.x) {
        int ty = tid >> 4, tx = tid & 15;
        out[((size_t)bz * N + ty0 + ty) * N + tx0 + tx] = 0.f;
        return;
    }

    // weights as bf16, A-fragment-friendly layout
    __shared__ __align__(16) short sW2[512];    // [oc=16][k=32], k = khkw*8 + ic
    __shared__ __align__(16) short sW3[1024];   // [oc=16][k=64], k = khkw*16 + ic (oc>=8 zero)
    __shared__ __align__(16) short h1s[324 * 8];   // [pos 18x18][8ch] bf16
    __shared__ __align__(16) short h2s[289 * 24];  // [pos 17x17][16ch used, pad->24] bf16
    __shared__ float ms[324];    // mask at h1 positions
    __shared__ float m2s[289];   // spread mask at h2 positions

    const float a1 = a1p[0], a2 = a2p[0], a3 = a3p[0];

    // --- stage transposed bf16 weights ---
    for (int t = tid; t < 512; t += 256) {
        int o = t >> 5, khkw = (t >> 3) & 3, i = t & 7;
        sW2[t] = f2bf(w2[((o * 8 + i) * 2 + (khkw >> 1)) * 2 + (khkw & 1)]);
    }
    for (int t = tid; t < 1024; t += 256) {
        int oc = t >> 6, k = t & 63, khkw = k >> 4, i = k & 15;
        sW3[t] = (oc < 8) ? f2bf(w3[((oc * 16 + i) * 2 + (khkw >> 1)) * 2 + (khkw & 1)]) : (short)0;
    }

    // --- Phase A: h1 (masked, PReLU'd, bf16) + mask into LDS (18x18 halo) ---
    for (int p = tid; p < 324; p += 256) {
        int dy = p / 18, dx = p - dy * 18;
        int gy = ty0 - 1 + dy, gx = tx0 - 1 + dx;
        float mv = 0.f, xv = 0.f;
        if ((unsigned)gy < N && (unsigned)gx < N) {
            size_t idx = ((size_t)bz * N + gy) * N + gx;
            mv = (maskg[idx] > 0) ? 1.f : 0.f;
            xv = xg[idx];
        }
        ms[p] = mv;
        short8 hv;
#pragma unroll
        for (int c = 0; c < 8; ++c) hv[c] = f2bf(mv * prelu(fmaf(xv, w1[c], b1[c]), a1));
        *(short8*)&h1s[p * 8] = hv;
    }
    __syncthreads();

    const int lane = tid & 63, wid = tid >> 6;
    const int c16 = lane & 15, g = lane >> 4;

    // --- Phase B: h2 at 17x17 positions via MFMA (K=32: 4 khkw x 8 ic) ---
    {
        short8 a2f = *(const short8*)&sW2[c16 * 32 + g * 8];
        const int kh = g >> 1, kw = g & 1;
        f32x4 bias2;
#pragma unroll
        for (int r = 0; r < 4; ++r) bias2[r] = b2[g * 4 + r];

        for (int G = wid * 5; G < wid * 5 + 5; ++G) {   // 20 groups of 16 positions
            int p = G * 16 + c16;
            bool valid = p < 289;
            int pc = valid ? p : 288;
            int dy2 = pc / 17, dx2 = pc - dy2 * 17;
            short8 bf = *(const short8*)&h1s[((dy2 + kh) * 18 + dx2 + kw) * 8];
            f32x4 acc = __builtin_amdgcn_mfma_f32_16x16x32_bf16(a2f, bf, bias2, 0, 0, 0);
            float m2v = fmaxf(fmaxf(ms[dy2 * 18 + dx2],       ms[dy2 * 18 + dx2 + 1]),
                              fmaxf(ms[(dy2 + 1) * 18 + dx2], ms[(dy2 + 1) * 18 + dx2 + 1]));
            int gx2 = tx0 - 1 + dx2;
            if (gx2 < 0 || gx2 > N - 2) m2v = 0.f;
            if (valid) {
                short4v hv;
#pragma unroll
                for (int r = 0; r < 4; ++r) hv[r] = f2bf(m2v * prelu(acc[r], a2));
                *(short4v*)&h2s[pc * 24 + g * 4] = hv;
                if (g == 0) m2s[pc] = m2v;
            }
        }
    }
    __syncthreads();

    // --- Phase C: h3 via 2 chained MFMAs (K=64) + layer4 + epilogue ---
    {
        short8 a3f0 = *(const short8*)&sW3[c16 * 64 + g * 8];        // k 0..31  (kh=0)
        short8 a3f1 = *(const short8*)&sW3[c16 * 64 + 32 + g * 8];   // k 32..63 (kh=1)
        const int kw = g >> 1, ic8 = g & 1;
        f32x4 bias3;
        float w4r[4];
#pragma unroll
        for (int r = 0; r < 4; ++r) {
            bias3[r] = (g < 2) ? b3[g * 4 + r] : 0.f;
            w4r[r]   = (g < 2) ? w4[g * 4 + r] : 0.f;
        }
        const float b4 = b4p[0];

        for (int G = wid * 4; G < wid * 4 + 4; ++G) {   // 16 output rows
            short8 bf0 = *(const short8*)&h2s[((G + 0) * 17 + c16 + kw) * 24 + ic8 * 8];
            short8 bf1 = *(const short8*)&h2s[((G + 1) * 17 + c16 + kw) * 24 + ic8 * 8];
            f32x4 acc = __builtin_amdgcn_mfma_f32_16x16x32_bf16(a3f0, bf0, bias3, 0, 0, 0);
            acc = __builtin_amdgcn_mfma_f32_16x16x32_bf16(a3f1, bf1, acc, 0, 0, 0);

            float partial = 0.f;
#pragma unroll
            for (int r = 0; r < 4; ++r) partial = fmaf(prelu(acc[r], a3), w4r[r], partial);
            partial += __shfl_xor(partial, 16, 64);
            partial += __shfl_xor(partial, 32, 64);

            float m3v = fmaxf(fmaxf(m2s[G * 17 + c16],       m2s[G * 17 + c16 + 1]),
                              fmaxf(m2s[(G + 1) * 17 + c16], m2s[(G + 1) * 17 + c16 + 1]));
            float outv = (partial + b4) * m3v;

            int y = ty0 + G, x = tx0 + c16;
            if (y < x) {
                outv = 0.f;
            } else if (y == x && m3v > 0.f) {
                outv = fmaxf(outv, 0.f) + log1pf(expf(-fabsf(outv)));
            }
            if (g == 0) out[((size_t)bz * N + y) * N + x] = outv;
        }
    }
}

extern "C" void kernel_launch(void* const* d_in, const int* in_sizes, int n_in,
                              void* d_out, int out_size, void* d_ws, size_t ws_size,
                              hipStream_t stream) {
    const float* x    = (const float*)d_in[0];
    const int*   mask = (const int*)  d_in[1];
    const float* w1   = (const float*)d_in[2];
    const float* b1   = (const float*)d_in[3];
    const float* a1   = (const float*)d_in[4];
    const float* w2   = (const float*)d_in[5];
    const float* b2   = (const float*)d_in[6];
    const float* a2   = (const float*)d_in[7];
    const float* w3   = (const float*)d_in[8];
    const float* b3   = (const float*)d_in[9];
    const float* a3   = (const float*)d_in[10];
    const float* w4   = (const float*)d_in[11];
    const float* b4   = (const float*)d_in[12];
    float* out = (float*)d_out;

    dim3 grid(N / TB, N / TB, 2);
    precond_mfma<<<grid, 256, 0, stream>>>(x, mask, w1, b1, a1, w2, b2, a2,
                                           w3, b3, a3, w4, b4, out);
}